// Round 2
// baseline (303.333 us; speedup 1.0000x reference)
//
#include <hip/hip_runtime.h>
#include <math.h>

// Problem constants (from reference)
#define T_STEPS   256
#define N_NEUR    2048
#define N_BATCH   32

// One thread per (batch, neuron), sequential scan over t=0..255 in registers.
// Input  layout: in[((b*T + t)*2 + s)*2048 + n]   (b,t,s,n)
// Output layout: out[(b*T + t)*2048 + n]
//
// R2: explicit software pipeline, prefetch depth D=16 steps (32 loads in
// flight per wave = 8 KB/wave, 32 KB/CU at 4 waves/CU) so the 1-wave/SIMD
// occupancy is latency-hidden by ILP instead of TLP. All loads/stores are
// nontemporal (pure streaming, no reuse).
//
// fp discipline: __fmul_rn/__fadd_rn keep mul/add separately rounded
// (reference numpy/XLA does not contract to FMA); binary outputs flip on
// ulp drift, so this is load-bearing. Verified absmax=0.0 in R1.
__global__ __launch_bounds__(256) void snn_scan_kernel(
    const float* __restrict__ in,
    float* __restrict__ out,
    float a_mem, float a_s0, float a_s1)
{
    constexpr int D = 16;                 // prefetch depth (timesteps)
    constexpr int STRIDE = 2 * N_NEUR;    // input elems per timestep per batch

    const int tid = blockIdx.x * blockDim.x + threadIdx.x;   // 0..65535
    const int n = tid & (N_NEUR - 1);
    const int b = tid >> 11;

    const float* pin = in + (size_t)b * T_STEPS * STRIDE + n;
    float* pout      = out + (size_t)b * T_STEPS * N_NEUR + n;

    float xa[D], xb[D];

    // Prologue: fill the pipeline with the first D timesteps.
    #pragma unroll
    for (int j = 0; j < D; ++j) {
        xa[j] = __builtin_nontemporal_load(&pin[j * STRIDE]);
        xb[j] = __builtin_nontemporal_load(&pin[j * STRIDE + N_NEUR]);
    }

    float vmem = 0.0f, i0 = 0.0f, i1 = 0.0f;

    #pragma unroll 1
    for (int blk = 0; blk < T_STEPS / D; ++blk) {
        const int tbase = blk * D;
        const bool pf = (blk + 1) < (T_STEPS / D);  // wave-uniform
        #pragma unroll
        for (int j = 0; j < D; ++j) {
            const float x0 = xa[j];
            const float x1 = xb[j];

            // Issue next-block loads immediately so they overlap the
            // dependent VALU chain and the spike stores.
            if (pf) {
                const int tf = tbase + D + j;
                xa[j] = __builtin_nontemporal_load(&pin[tf * STRIDE]);
                xb[j] = __builtin_nontemporal_load(&pin[tf * STRIDE + N_NEUR]);
            }

            // isyn = alpha_syn * isyn + x   (separate mul/add rounding)
            i0 = __fadd_rn(__fmul_rn(a_s0, i0), x0);
            i1 = __fadd_rn(__fmul_rn(a_s1, i1), x1);

            // vmem = alpha_mem * vmem + (i0 + i1)
            const float ssum = __fadd_rn(i0, i1);
            vmem = __fadd_rn(__fmul_rn(a_mem, vmem), ssum);

            // spike = (vmem - 1 > 0); vmem -= spike
            const float vs = __fsub_rn(vmem, 1.0f);
            const bool fired = (vs > 0.0f);
            __builtin_nontemporal_store(fired ? 1.0f : 0.0f,
                                        &pout[(tbase + j) * N_NEUR]);
            vmem = fired ? vs : vmem;
        }
    }
}

extern "C" void kernel_launch(void* const* d_in, const int* in_sizes, int n_in,
                              void* d_out, int out_size, void* d_ws, size_t ws_size,
                              hipStream_t stream) {
    const float* in = (const float*)d_in[0];
    float* out = (float*)d_out;

    // Correctly-rounded float32 decay constants of exp on the float32-rounded
    // argument: matches jnp.exp(jnp.float32(-1/tau)).
    const float a_s0  = (float)exp((double)(-1.0f / 5.0f));   // tau_syn[0] = 5
    const float a_s1  = (float)exp((double)(-1.0f / 10.0f));  // tau_syn[1] = 10
    const float a_mem = (float)exp((double)(-1.0f / 10.0f));  // tau_mem    = 10

    const int total_threads = N_BATCH * N_NEUR;  // 65536 = 1024 waves
    dim3 block(256);
    dim3 grid(total_threads / 256);              // 256 blocks -> 1 per CU

    snn_scan_kernel<<<grid, block, 0, stream>>>(in, out, a_mem, a_s0, a_s1);
}

// Round 3
// 209.841 us; speedup vs baseline: 1.4455x; 1.4455x over previous
//
#include <hip/hip_runtime.h>
#include <math.h>

// Problem constants (from reference)
#define T_STEPS 256
#define N_NEUR  2048
#define N_BATCH 32
#define STRIDE  (2 * N_NEUR)   // input floats per (b, t)

#define TT      16             // timesteps per LDS tile
#define NTILE   (T_STEPS / TT) // 16 tiles
#define BN      256            // neurons per block

// Async 16B global->LDS DMA (global_load_lds_dwordx4). LDS dest is
// wave-uniform base + lane*16 — our mapping is exactly lane-contiguous.
__device__ __forceinline__ void async_cp16(const float* g, float* l) {
    __builtin_amdgcn_global_load_lds(
        (const __attribute__((address_space(1))) void*)g,
        (__attribute__((address_space(3))) void*)l,
        16, 0, 0);
}

// Block = one (batch b, neuron slice n0..n0+255). Thread = one neuron.
// Double-buffered LDS tiles of TT timesteps; per tile: issue next tile's
// DMA, compute current tile from LDS, __syncthreads (its vmcnt(0) drain
// completes the DMA). Memory latency is paid once per 16-step tile, not
// per step — R1/R2 showed the compiler serializes per-step global loads
// against the recurrence (~1 latency/step).
//
// fp discipline: __fmul_rn/__fadd_rn keep mul/add separately rounded
// (reference does not contract to FMA); binary outputs flip on ulp drift.
// Verified absmax=0.0 in R1/R2 — do not touch the arithmetic.
__global__ __launch_bounds__(256) void snn_scan_kernel(
    const float* __restrict__ in,
    float* __restrict__ out,
    float a_mem, float a_s0, float a_s1)
{
    // 2 buffers x (TT*2*BN) floats = 2 x 32 KB = 64 KB
    __shared__ float buf[2][TT * 2 * BN];

    const int tid = threadIdx.x;
    const int bid = blockIdx.x;          // 256 blocks -> 1 per CU
    const int b   = bid >> 3;            // batch
    const int n0  = (bid & 7) << 8;      // neuron slice base

    const float* gin = in + (size_t)b * T_STEPS * STRIDE + n0;
    float* pout      = out + (size_t)b * T_STEPS * N_NEUR + n0 + tid;

    // Staging map: DMA j covers t_local = 2j + (tid>>7), s = (tid>>6)&1,
    // 16B lane chunk (tid&63)*4 floats. Global offset (floats):
    const int toff = (tid >> 7) * STRIDE + ((tid >> 6) & 1) * N_NEUR + (tid & 63) * 4;
    // LDS float offset for DMA j: j*1024 + tid*4  (layout [t_local][s][n])
    const int ldsf = tid * 4;

    // Prologue: stage tile 0 into buf[0]
    #pragma unroll
    for (int j = 0; j < TT / 2; ++j) {
        async_cp16(gin + (size_t)(2 * j) * STRIDE + toff, &buf[0][j * 1024 + ldsf]);
    }
    __syncthreads();   // vmcnt(0) drain: tile 0 resident

    float vmem = 0.0f, i0 = 0.0f, i1 = 0.0f;

    #pragma unroll
    for (int k = 0; k < NTILE; ++k) {
        // Issue next tile's DMA into the other buffer (overlaps this tile's compute)
        if (k + 1 < NTILE) {
            const float* gt = gin + (size_t)(k + 1) * TT * STRIDE + toff;
            float* lb = &buf[(k + 1) & 1][0];
            #pragma unroll
            for (int j = 0; j < TT / 2; ++j) {
                async_cp16(gt + (size_t)(2 * j) * STRIDE, lb + j * 1024 + ldsf);
            }
        }

        const float* lb = &buf[k & 1][0];
        float* po = pout + (size_t)k * TT * N_NEUR;

        #pragma unroll
        for (int t = 0; t < TT; ++t) {
            // [t][s][n] layout: stride-1 across lanes -> conflict-free
            const float x0 = lb[t * 512 + tid];
            const float x1 = lb[t * 512 + 256 + tid];

            // isyn = alpha_syn * isyn + x   (separate mul/add rounding)
            i0 = __fadd_rn(__fmul_rn(a_s0, i0), x0);
            i1 = __fadd_rn(__fmul_rn(a_s1, i1), x1);

            // vmem = alpha_mem * vmem + (i0 + i1)
            const float ssum = __fadd_rn(i0, i1);
            vmem = __fadd_rn(__fmul_rn(a_mem, vmem), ssum);

            // spike = (vmem - 1 > 0); vmem -= spike
            const float vs = __fsub_rn(vmem, 1.0f);
            const bool fired = (vs > 0.0f);
            po[(size_t)t * N_NEUR] = fired ? 1.0f : 0.0f;
            vmem = fired ? vs : vmem;
        }
        __syncthreads();   // drains vmcnt: next tile's DMA complete; buffer reuse safe
    }
}

extern "C" void kernel_launch(void* const* d_in, const int* in_sizes, int n_in,
                              void* d_out, int out_size, void* d_ws, size_t ws_size,
                              hipStream_t stream) {
    const float* in = (const float*)d_in[0];
    float* out = (float*)d_out;

    // Correctly-rounded float32 decay constants of exp on the float32-rounded
    // argument: matches jnp.exp(jnp.float32(-1/tau)).
    const float a_s0  = (float)exp((double)(-1.0f / 5.0f));   // tau_syn[0] = 5
    const float a_s1  = (float)exp((double)(-1.0f / 10.0f));  // tau_syn[1] = 10
    const float a_mem = (float)exp((double)(-1.0f / 10.0f));  // tau_mem    = 10

    dim3 block(256);
    dim3 grid(N_BATCH * (N_NEUR / BN));  // 256 blocks

    snn_scan_kernel<<<grid, block, 0, stream>>>(in, out, a_mem, a_s0, a_s1);
}